// Round 16
// baseline (25963.943 us; speedup 1.0000x reference)
//
#include <hip/hip_runtime.h>
#include <cstdint>

#define NBLK 128
#define BLOCK 1024
#define ROWS 32            // hidden rows per block: 128*32 = 4096
#define HDIM 4096
#define IDIM 64
#define ODIM 16
#define TSTEPS 4096
#define PAD 576            // 18 groups * 32 slots (bank-dealt ELL)
#define GMAX 18
#define LEAK 0.9f
#define SUN 16             // s units per producer: one per wave {s_2w, s_2w+1, spare, tag}
#define YU 8               // y units per producer: 2 vals + tag + pad
#define SPAD 34            // padded words per 32-value producer chunk in s_lds

typedef float f32x4 __attribute__((ext_vector_type(4)));

// zero the tagged-exchange region every launch (tags use ==, so 0/poison never match)
__global__ void init_ws(float* ws) {
    int i = blockIdx.x * blockDim.x + threadIdx.x;
    if (i < (2 * NBLK * SUN + 2 * NBLK * YU) * 4) ws[i] = 0.0f;
}

__global__ __launch_bounds__(BLOCK) void esn_kernel(
    const float* __restrict__ X,     // [T][I]
    const float* __restrict__ Win,   // [H][I]
    const float* __restrict__ Wres,  // [H][H]
    const float* __restrict__ bvec,  // [H]
    const float* __restrict__ Wfb,   // [H][O]
    const float* __restrict__ Wout,  // [O][H]
    float* __restrict__ out,         // results [T][O] then outputs [T][H]
    float* __restrict__ sx,          // [2][NBLK][SUN] tagged f32x4 units (s exchange)
    float* __restrict__ yx)          // [2][NBLK][YU]  tagged f32x4 units (y partials)
{
    __shared__ float          ell_val[ROWS][PAD];       // 73728 B
    __shared__ unsigned short ell_idx[ROWS][PAD];       // 36864 B (stores PADDED idx)
    __shared__ __align__(16) float s_lds[2][NBLK*SPAD]; // 34816 B (bank-padded chunks)
    __shared__ float          win_lds[ROWS][IDIM];      //  8192 B
    __shared__ float          wfb_lds[ROWS][ODIM];      //  2048 B
    __shared__ __align__(8)  float wout_lds[ROWS][ODIM];//  2048 B ([r][o])
    __shared__ float          b_lds[ROWS];
    __shared__ float          x_lds[2][IDIM];           //  512 B (double buffer)
    __shared__ float          y_lds[2][ODIM];           //  128 B (double buffer)
    __shared__ __align__(8)  float ytmp[16][18];        //  1152 B (per-wave y contribs, padded)
    __shared__ unsigned       done[16];                 // per-wave phase-B completion (LDS)
    __shared__ int            nnz_lds[ROWS];
    __shared__ int            rnds_lds[ROWS];
    __shared__ unsigned char  bankCnt[ROWS][32];        // build only
    __shared__ unsigned char  grpCnt[ROWS][GMAX];       // build only

    const int tid   = threadIdx.x;
    const int blk   = blockIdx.x;
    const int rbase = blk * ROWS;
    const int rowB  = tid >> 5;        // 0..31
    const int lB    = tid & 31;
    const int wv    = tid >> 6;        // 0..15
    const int ln    = tid & 63;

    // ---- pass 0: zero ELL + counters ----
    for (int i = tid; i < ROWS * PAD; i += BLOCK) {
        ell_val[i / PAD][i % PAD] = 0.0f;
        ell_idx[i / PAD][i % PAD] = 0;
    }
    for (int i = tid; i < ROWS * 32; i += BLOCK) bankCnt[i >> 5][i & 31] = 0;
    for (int i = tid; i < ROWS * GMAX; i += BLOCK) grpCnt[i / GMAX][i % GMAX] = 0;
    if (tid < 16) done[tid] = 0u;

    // ---- pass 1 (parallel): nnz per row ----
    for (int rr = wv * 2; rr < wv * 2 + 2; ++rr) {
        const float* wrow = Wres + (size_t)(rbase + rr) * HDIM;
        int cnt = 0;
        for (int c0 = 0; c0 < HDIM; c0 += 64)
            cnt += __popcll(__ballot(wrow[c0 + ln] != 0.0f));
        if (ln == 0) {
            int nz = cnt < PAD ? cnt : PAD;
            nnz_lds[rr] = nz;
            int gu = (nz + 31) >> 5;
            if (gu < 1) gu = 1;
            if (gu > GMAX) gu = GMAX;
            rnds_lds[rr] = (gu + 1) >> 1;
        }
    }
    __syncthreads();

    // ---- pass 2 (serial per row, deterministic): bank-balanced deal on PADDED banks ----
    if (ln == 0 || ln == 32) {
        const int row = wv * 2 + (ln >> 5);
        const int nz  = nnz_lds[row];
        int gu = (nz + 31) >> 5;
        if (gu < 1) gu = 1;
        if (gu > GMAX) gu = GMAX;
        const float* wrow = Wres + (size_t)(rbase + row) * HDIM;
        int placed = 0;
        for (int c = 0; c < HDIM && placed < nz; ++c) {
            const float w = wrow[c];
            if (w != 0.0f) {
                const int pidx = c + 2 * (c >> 5);       // padded word index (SPAD=34)
                const int b = pidx & 31;                 // bank of the padded gather
                const int r = bankCnt[row][b];
                bankCnt[row][b] = (unsigned char)(r + 1);
                int g = r % gu;
                int p = grpCnt[row][g];
                int guard = 0;
                while (p >= 32 && guard < GMAX) {
                    g = (g + 1 == gu) ? 0 : g + 1;
                    p = grpCnt[row][g];
                    ++guard;
                }
                if (p >= 32) break;
                grpCnt[row][g] = (unsigned char)(p + 1);
                const int slot = ((g >> 1) << 6) + 2 * p + (g & 1);
                ell_val[row][slot] = w;
                ell_idx[row][slot] = (unsigned short)pidx;
                ++placed;
            }
        }
    }

    // ---- small weights into LDS ----
    for (int i = tid; i < ROWS * IDIM; i += BLOCK)
        win_lds[i >> 6][i & 63] = Win[(size_t)(rbase + (i >> 6)) * IDIM + (i & 63)];
    for (int i = tid; i < ROWS * ODIM; i += BLOCK)
        wfb_lds[i >> 4][i & 15] = Wfb[(size_t)(rbase + (i >> 4)) * ODIM + (i & 15)];
    for (int i = tid; i < ROWS * ODIM; i += BLOCK)   // [r][o] = Wout[o][rbase+r]
        wout_lds[i >> 4][i & 15] = Wout[(size_t)(i & 15) * HDIM + rbase + (i >> 4)];
    if (tid < ROWS) b_lds[tid] = bvec[rbase + tid];

    // ---- prologue: s_{-1}=0 (both buffers, flat), y_{-1}=0, x_0 ----
    {
        float* sz = &s_lds[0][0];
        for (int i = tid; i < 2 * NBLK * SPAD; i += BLOCK) sz[i] = 0.0f;
    }
    if (tid < ODIM) y_lds[0][tid] = 0.0f;
    if (tid >= 64 && tid < 128) x_lds[0][tid - 64] = X[tid - 64];
    __syncthreads();

    float* out_res = out;
    float* out_s   = out + (size_t)TSTEPS * ODIM;
    const int RB = rnds_lds[rowB];

    for (int t = 0; t < TSTEPS; ++t) {
        const unsigned tu = (unsigned)(t + 1);
        const float tagf = __uint_as_float(tu);
        const int cur = t & 1, nxt = cur ^ 1;

        // ---- phase B: gather, reduce; per-wave INLINE publish of s-unit + y-contrib ----
        {
            const float* sc = s_lds[cur];
            float a0 = 0.0f, a1 = 0.0f;
            for (int k = 0; k < RB; ++k) {
                const int e = (k << 6) + (lB << 1);
                const float2  v  = *(const float2*)&ell_val[rowB][e];
                const ushort2 ix = *(const ushort2*)&ell_idx[rowB][e];  // padded idx
                a0 += v.x * sc[ix.x];
                a1 += v.y * sc[ix.y];
            }
            float acc = a0 + a1;
            acc += win_lds[rowB][lB] * x_lds[cur][lB]
                 + win_lds[rowB][lB + 32] * x_lds[cur][lB + 32];
            if (lB < ODIM) acc += wfb_lds[rowB][lB] * y_lds[cur][lB];
            acc += __shfl_xor(acc, 16, 32);
            acc += __shfl_xor(acc, 8, 32);
            acc += __shfl_xor(acc, 4, 32);
            acc += __shfl_xor(acc, 2, 32);
            acc += __shfl_xor(acc, 1, 32);
            // all lanes of each 32-half now hold the row sum
            const float pre = acc + b_lds[rowB];
            const float snAll = (1.0f - LEAK) * sc[blk * SPAD + rowB] + LEAK * tanhf(pre);
            const float sn0 = __shfl(snAll, 0);    // row 2w
            const float sn1 = __shfl(snAll, 32);   // row 2w+1
            if (ln < 16)                           // wave's y contribution (order = r asc)
                ytmp[wv][ln] = wout_lds[2 * wv][ln] * sn0 + wout_lds[2 * wv + 1][ln] * sn1;
            if (ln == 0) {
                f32x4 v; v.x = sn0; v.y = sn1; v.z = 0.0f; v.w = tagf;   // tag in .w
                float* dst = sx + (((size_t)cur * NBLK + blk) * SUN + wv) * 4;
                asm volatile("global_store_dwordx4 %0, %1, off sc0 sc1"
                             :: "v"(dst), "v"(v) : "memory");
                float2 o2; o2.x = sn0; o2.y = sn1;   // out_s (plain cached store)
                *(float2*)(out_s + (size_t)t * HDIM + rbase + 2 * wv) = o2;
                __hip_atomic_store(&done[wv], tu, __ATOMIC_RELEASE,
                                   __HIP_MEMORY_SCOPE_WORKGROUP);  // orders ytmp writes
            }
        }
        // NO B-sync: waves proceed straight to their exchange roles.

        if (wv == 0) {
            // ---- y publisher: wait 16 LDS flags, sum ytmp, publish; then x prefetch ----
            float xv = 0.0f;
            if (t + 1 < TSTEPS) xv = X[(size_t)(t + 1) * IDIM + ln];   // issue early
            for (;;) {
                unsigned f = (ln < 16)
                    ? __hip_atomic_load(&done[ln], __ATOMIC_ACQUIRE, __HIP_MEMORY_SCOPE_WORKGROUP)
                    : tu;
                if (__all(f >= tu)) break;
            }
            if (ln < YU) {
                float a0 = 0.0f, a1 = 0.0f;
                #pragma unroll
                for (int w = 0; w < 16; ++w) {       // order = w asc = r asc
                    const float2 p = *(const float2*)&ytmp[w][2 * ln];
                    a0 += p.x;
                    a1 += p.y;
                }
                f32x4 v; v.x = a0; v.y = a1; v.z = tagf; v.w = 0.0f;   // tag in .z
                float* dst = yx + (((size_t)cur * NBLK + blk) * YU + ln) * 4;
                asm volatile("global_store_dwordx4 %0, %1, off sc0 sc1"
                             :: "v"(dst), "v"(v) : "memory");
            }
            if (t + 1 < TSTEPS) x_lds[nxt][ln] = xv;
        } else if (wv == 1) {
            // ---- y-reduce: poll 128 y units in 4 predicated groups, butterfly ----
            const int u  = ln & 7;
            const int pg = ln >> 3;                    // 8 producer groups of 16
            const float* yb = yx + (size_t)cur * NBLK * YU * 4;
            f32x4 w0,w1,w2,w3,w4,w5,w6,w7,w8,w9,w10,w11,w12,w13,w14,w15;
            bool k0 = false, k1 = false, k2 = false, k3 = false;
            #define YL(i) asm volatile("global_load_dwordx4 %0, %1, off sc0 sc1" \
                : "=v"(w##i) : "v"(yb + (((pg << 4) + i) * YU + u) * 4));
            for (;;) {
                if (!k0) { YL(0) YL(1) YL(2) YL(3) }
                if (!k1) { YL(4) YL(5) YL(6) YL(7) }
                if (!k2) { YL(8) YL(9) YL(10) YL(11) }
                if (!k3) { YL(12) YL(13) YL(14) YL(15) }
                asm volatile("s_waitcnt vmcnt(0)" ::: "memory");
                __builtin_amdgcn_sched_barrier(0);
                k0 = k0 || (__float_as_uint(w0.z) == tu  && __float_as_uint(w1.z) == tu
                         && __float_as_uint(w2.z) == tu  && __float_as_uint(w3.z) == tu);
                k1 = k1 || (__float_as_uint(w4.z) == tu  && __float_as_uint(w5.z) == tu
                         && __float_as_uint(w6.z) == tu  && __float_as_uint(w7.z) == tu);
                k2 = k2 || (__float_as_uint(w8.z) == tu  && __float_as_uint(w9.z) == tu
                         && __float_as_uint(w10.z) == tu && __float_as_uint(w11.z) == tu);
                k3 = k3 || (__float_as_uint(w12.z) == tu && __float_as_uint(w13.z) == tu
                         && __float_as_uint(w14.z) == tu && __float_as_uint(w15.z) == tu);
                if (__all(k0 && k1 && k2 && k3)) break;
            }
            #undef YL
            float acc0 = ((w0.x + w1.x) + (w2.x + w3.x)) + ((w4.x + w5.x) + (w6.x + w7.x))
                       + ((w8.x + w9.x) + (w10.x + w11.x)) + ((w12.x + w13.x) + (w14.x + w15.x));
            float acc1 = ((w0.y + w1.y) + (w2.y + w3.y)) + ((w4.y + w5.y) + (w6.y + w7.y))
                       + ((w8.y + w9.y) + (w10.y + w11.y)) + ((w12.y + w13.y) + (w14.y + w15.y));
            acc0 += __shfl_xor(acc0, 8);  acc1 += __shfl_xor(acc1, 8);
            acc0 += __shfl_xor(acc0, 16); acc1 += __shfl_xor(acc1, 16);
            acc0 += __shfl_xor(acc0, 32); acc1 += __shfl_xor(acc1, 32);
            if (ln < 8) {
                if (t + 1 < TSTEPS) { y_lds[nxt][2 * u] = acc0; y_lds[nxt][2 * u + 1] = acc1; }
                if (blk == 0) {
                    out_res[(size_t)t * ODIM + 2 * u]     = acc0;
                    out_res[(size_t)t * ODIM + 2 * u + 1] = acc1;
                }
            }
        } else {
            // ---- s-consumer: predicated poll; scatter each unit as it arrives ----
            if (t + 1 < TSTEPS) {
                const int wi    = wv - 2;                        // 0..13
                const int start = (wi < 2) ? wi * 10 : 20 + (wi - 2) * 9;
                const int count = (wi < 2) ? 10 : 9;             // 2*10 + 12*9 = 128
                const int U     = count * SUN;                   // 160 or 144
                const float* sb = sx + ((size_t)cur * NBLK + start) * SUN * 4;
                float* sd = s_lds[nxt];
                const int g0 = ln, g1 = ln + 64, g2 = ln + 128;
                bool k0 = false, k1 = (g1 >= U), k2 = (g2 >= U);
                f32x4 v0, v1, v2;
                for (;;) {
                    if (!k0) asm volatile("global_load_dwordx4 %0, %1, off sc0 sc1"
                                          : "=v"(v0) : "v"(sb + (size_t)g0 * 4));
                    if (!k1) asm volatile("global_load_dwordx4 %0, %1, off sc0 sc1"
                                          : "=v"(v1) : "v"(sb + (size_t)g1 * 4));
                    if (!k2) asm volatile("global_load_dwordx4 %0, %1, off sc0 sc1"
                                          : "=v"(v2) : "v"(sb + (size_t)g2 * 4));
                    asm volatile("s_waitcnt vmcnt(0)" ::: "memory");
                    __builtin_amdgcn_sched_barrier(0);
                    if (!k0 && __float_as_uint(v0.w) == tu) {
                        k0 = true;
                        const int pp = start + (g0 >> 4), u = g0 & 15;
                        float2 s2; s2.x = v0.x; s2.y = v0.y;
                        *(float2*)&sd[pp * SPAD + 2 * u] = s2;
                    }
                    if (!k1 && __float_as_uint(v1.w) == tu) {
                        k1 = true;
                        const int pp = start + (g1 >> 4), u = g1 & 15;
                        float2 s2; s2.x = v1.x; s2.y = v1.y;
                        *(float2*)&sd[pp * SPAD + 2 * u] = s2;
                    }
                    if (!k2 && __float_as_uint(v2.w) == tu) {
                        k2 = true;
                        const int pp = start + (g2 >> 4), u = g2 & 15;
                        float2 s2; s2.x = v2.x; s2.y = v2.y;
                        *(float2*)&sd[pp * SPAD + 2 * u] = s2;
                    }
                    if (__all(k0 && k1 && k2)) break;
                }
            }
        }
        __syncthreads();   // A-sync: s/x/y for t+1 ready; gates exchange-buffer reuse
    }
}

extern "C" void kernel_launch(void* const* d_in, const int* in_sizes, int n_in,
                              void* d_out, int out_size, void* d_ws, size_t ws_size,
                              hipStream_t stream) {
    (void)in_sizes; (void)n_in; (void)out_size; (void)ws_size;
    const float* X    = (const float*)d_in[0];
    const float* Win  = (const float*)d_in[1];
    const float* Wres = (const float*)d_in[2];
    const float* b    = (const float*)d_in[3];
    const float* Wfb  = (const float*)d_in[4];
    const float* Wout = (const float*)d_in[5];
    float* out = (float*)d_out;
    float* sx  = (float*)d_ws;                          // 2*128*16*16B = 64 KiB
    float* yx  = (float*)d_ws + 2 * NBLK * SUN * 4;     // 2*128*8*16B  = 32 KiB

    const int words = (2 * NBLK * SUN + 2 * NBLK * YU) * 4;
    init_ws<<<(words + 255) / 256, 256, 0, stream>>>((float*)d_ws);
    esn_kernel<<<NBLK, BLOCK, 0, stream>>>(X, Win, Wres, b, Wfb, Wout, out, sx, yx);
}

// Round 17
// 20638.208 us; speedup vs baseline: 1.2581x; 1.2581x over previous
//
#include <hip/hip_runtime.h>
#include <cstdint>

#define NBLK 128
#define BLOCK 1024
#define ROWS 32            // hidden rows per block: 128*32 = 4096
#define HDIM 4096
#define IDIM 64
#define ODIM 16
#define TSTEPS 4096
#define PAD 576            // 18 groups * 32 slots (bank-dealt ELL)
#define GMAX 18
#define LEAK 0.9f
#define SUN 16             // s units per producer: one per wave {s_2w, s_2w+1, spare, tag}
#define YU 8               // y units per producer: 2 vals + tag + pad
#define SPAD 34            // padded words per 32-value producer chunk in s_lds

typedef float f32x4 __attribute__((ext_vector_type(4)));

// zero the tagged-exchange region every launch (tags use ==, so 0/poison never match)
__global__ void init_ws(float* ws) {
    int i = blockIdx.x * blockDim.x + threadIdx.x;
    if (i < (2 * NBLK * SUN + 2 * NBLK * YU) * 4) ws[i] = 0.0f;
}

__global__ __launch_bounds__(BLOCK) void esn_kernel(
    const float* __restrict__ X,     // [T][I]
    const float* __restrict__ Win,   // [H][I]
    const float* __restrict__ Wres,  // [H][H]
    const float* __restrict__ bvec,  // [H]
    const float* __restrict__ Wfb,   // [H][O]
    const float* __restrict__ Wout,  // [O][H]
    float* __restrict__ out,         // results [T][O] then outputs [T][H]
    float* __restrict__ sx,          // [2][NBLK][SUN] tagged f32x4 units (s exchange)
    float* __restrict__ yx)          // [2][NBLK][YU]  tagged f32x4 units (y partials)
{
    __shared__ float          ell_val[ROWS][PAD];       // 73728 B
    __shared__ unsigned short ell_idx[ROWS][PAD];       // 36864 B (stores PADDED idx)
    __shared__ __align__(16) float s_lds[2][NBLK*SPAD]; // 34816 B (bank-padded chunks)
    __shared__ float          win_lds[ROWS][IDIM];      //  8192 B
    __shared__ float          wfb_lds[ROWS][ODIM];      //  2048 B
    __shared__ __align__(8)  float wout_lds[ROWS][ODIM];//  2048 B ([r][o])
    __shared__ float          b_lds[ROWS];
    __shared__ float          x_lds[2][IDIM];           //  512 B (double buffer)
    __shared__ float          y_lds[2][ODIM];           //  128 B (double buffer)
    __shared__ __align__(8)  float ytmp[16][18];        //  1152 B (per-wave y contribs, padded)
    __shared__ unsigned       done[16];                 // per-wave phase-B completion (LDS)
    __shared__ int            nnz_lds[ROWS];
    __shared__ int            rnds_lds[ROWS];
    __shared__ unsigned char  bankCnt[ROWS][32];        // build only
    __shared__ unsigned char  grpCnt[ROWS][GMAX];       // build only

    const int tid   = threadIdx.x;
    const int blk   = blockIdx.x;
    const int rbase = blk * ROWS;
    const int rowB  = tid >> 5;        // 0..31
    const int lB    = tid & 31;
    const int wv    = tid >> 6;        // 0..15
    const int ln    = tid & 63;

    // ---- pass 0: zero ELL + counters ----
    for (int i = tid; i < ROWS * PAD; i += BLOCK) {
        ell_val[i / PAD][i % PAD] = 0.0f;
        ell_idx[i / PAD][i % PAD] = 0;
    }
    for (int i = tid; i < ROWS * 32; i += BLOCK) bankCnt[i >> 5][i & 31] = 0;
    for (int i = tid; i < ROWS * GMAX; i += BLOCK) grpCnt[i / GMAX][i % GMAX] = 0;
    if (tid < 16) done[tid] = 0u;

    // ---- pass 1 (parallel): nnz per row ----
    for (int rr = wv * 2; rr < wv * 2 + 2; ++rr) {
        const float* wrow = Wres + (size_t)(rbase + rr) * HDIM;
        int cnt = 0;
        for (int c0 = 0; c0 < HDIM; c0 += 64)
            cnt += __popcll(__ballot(wrow[c0 + ln] != 0.0f));
        if (ln == 0) {
            int nz = cnt < PAD ? cnt : PAD;
            nnz_lds[rr] = nz;
            int gu = (nz + 31) >> 5;
            if (gu < 1) gu = 1;
            if (gu > GMAX) gu = GMAX;
            rnds_lds[rr] = (gu + 1) >> 1;
        }
    }
    __syncthreads();

    // ---- pass 2 (serial per row, deterministic): bank-balanced deal on PADDED banks ----
    if (ln == 0 || ln == 32) {
        const int row = wv * 2 + (ln >> 5);
        const int nz  = nnz_lds[row];
        int gu = (nz + 31) >> 5;
        if (gu < 1) gu = 1;
        if (gu > GMAX) gu = GMAX;
        const float* wrow = Wres + (size_t)(rbase + row) * HDIM;
        int placed = 0;
        for (int c = 0; c < HDIM && placed < nz; ++c) {
            const float w = wrow[c];
            if (w != 0.0f) {
                const int pidx = c + 2 * (c >> 5);       // padded word index (SPAD=34)
                const int b = pidx & 31;                 // bank of the padded gather
                const int r = bankCnt[row][b];
                bankCnt[row][b] = (unsigned char)(r + 1);
                int g = r % gu;
                int p = grpCnt[row][g];
                int guard = 0;
                while (p >= 32 && guard < GMAX) {
                    g = (g + 1 == gu) ? 0 : g + 1;
                    p = grpCnt[row][g];
                    ++guard;
                }
                if (p >= 32) break;
                grpCnt[row][g] = (unsigned char)(p + 1);
                const int slot = ((g >> 1) << 6) + 2 * p + (g & 1);
                ell_val[row][slot] = w;
                ell_idx[row][slot] = (unsigned short)pidx;
                ++placed;
            }
        }
    }

    // ---- small weights into LDS ----
    for (int i = tid; i < ROWS * IDIM; i += BLOCK)
        win_lds[i >> 6][i & 63] = Win[(size_t)(rbase + (i >> 6)) * IDIM + (i & 63)];
    for (int i = tid; i < ROWS * ODIM; i += BLOCK)
        wfb_lds[i >> 4][i & 15] = Wfb[(size_t)(rbase + (i >> 4)) * ODIM + (i & 15)];
    for (int i = tid; i < ROWS * ODIM; i += BLOCK)   // [r][o] = Wout[o][rbase+r]
        wout_lds[i >> 4][i & 15] = Wout[(size_t)(i & 15) * HDIM + rbase + (i >> 4)];
    if (tid < ROWS) b_lds[tid] = bvec[rbase + tid];

    // ---- prologue: s_{-1}=0 (both buffers, flat), y_{-1}=0, x_0 ----
    {
        float* sz = &s_lds[0][0];
        for (int i = tid; i < 2 * NBLK * SPAD; i += BLOCK) sz[i] = 0.0f;
    }
    if (tid < ODIM) y_lds[0][tid] = 0.0f;
    if (tid >= 64 && tid < 128) x_lds[0][tid - 64] = X[tid - 64];
    __syncthreads();

    float* out_res = out;
    float* out_s   = out + (size_t)TSTEPS * ODIM;
    const int RB = rnds_lds[rowB];

    for (int t = 0; t < TSTEPS; ++t) {
        const unsigned tu = (unsigned)(t + 1);
        const float tagf = __uint_as_float(tu);
        const int cur = t & 1, nxt = cur ^ 1;

        // ---- phase B: gather, reduce; per-wave INLINE publish of s-unit + y-contrib ----
        {
            const float* sc = s_lds[cur];
            float a0 = 0.0f, a1 = 0.0f;
            for (int k = 0; k < RB; ++k) {
                const int e = (k << 6) + (lB << 1);
                const float2  v  = *(const float2*)&ell_val[rowB][e];
                const ushort2 ix = *(const ushort2*)&ell_idx[rowB][e];  // padded idx
                a0 += v.x * sc[ix.x];
                a1 += v.y * sc[ix.y];
            }
            float acc = a0 + a1;
            acc += win_lds[rowB][lB] * x_lds[cur][lB]
                 + win_lds[rowB][lB + 32] * x_lds[cur][lB + 32];
            if (lB < ODIM) acc += wfb_lds[rowB][lB] * y_lds[cur][lB];
            acc += __shfl_xor(acc, 16, 32);
            acc += __shfl_xor(acc, 8, 32);
            acc += __shfl_xor(acc, 4, 32);
            acc += __shfl_xor(acc, 2, 32);
            acc += __shfl_xor(acc, 1, 32);
            // all lanes of each 32-half now hold the row sum
            const float pre = acc + b_lds[rowB];
            const float snAll = (1.0f - LEAK) * sc[blk * SPAD + rowB] + LEAK * tanhf(pre);
            const float sn0 = __shfl(snAll, 0);    // row 2w
            const float sn1 = __shfl(snAll, 32);   // row 2w+1
            if (ln < 16)                           // wave's y contribution (order = r asc)
                ytmp[wv][ln] = wout_lds[2 * wv][ln] * sn0 + wout_lds[2 * wv + 1][ln] * sn1;
            if (ln == 0) {
                f32x4 v; v.x = sn0; v.y = sn1; v.z = 0.0f; v.w = tagf;   // tag in .w
                float* dst = sx + (((size_t)cur * NBLK + blk) * SUN + wv) * 4;
                asm volatile("global_store_dwordx4 %0, %1, off sc0 sc1"
                             :: "v"(dst), "v"(v) : "memory");
                float2 o2; o2.x = sn0; o2.y = sn1;   // out_s (plain cached store)
                *(float2*)(out_s + (size_t)t * HDIM + rbase + 2 * wv) = o2;
                __hip_atomic_store(&done[wv], tu, __ATOMIC_RELEASE,
                                   __HIP_MEMORY_SCOPE_WORKGROUP);  // orders ytmp writes
            }
        }
        // NO B-sync: waves proceed straight to their exchange roles.

        if (wv == 0) {
            // ---- y publisher: wait 16 LDS flags (cheap), sum ytmp, publish units ----
            for (;;) {
                unsigned f = (ln < 16)
                    ? __hip_atomic_load(&done[ln], __ATOMIC_ACQUIRE, __HIP_MEMORY_SCOPE_WORKGROUP)
                    : tu;
                if (__all(f >= tu)) break;
            }
            if (ln < YU) {
                float a0 = 0.0f, a1 = 0.0f;
                #pragma unroll
                for (int w = 0; w < 16; ++w) {       // order = w asc = r asc
                    const float2 p = *(const float2*)&ytmp[w][2 * ln];
                    a0 += p.x;
                    a1 += p.y;
                }
                f32x4 v; v.x = a0; v.y = a1; v.z = tagf; v.w = 0.0f;   // tag in .z
                float* dst = yx + (((size_t)cur * NBLK + blk) * YU + ln) * 4;
                asm volatile("global_store_dwordx4 %0, %1, off sc0 sc1"
                             :: "v"(dst), "v"(v) : "memory");
            }
        } else if (wv == 1) {
            // ---- y-reduce: x[nxt] prefetch; poll all 128 y units; butterfly ----
            if (t + 1 < TSTEPS) x_lds[nxt][ln] = X[(size_t)(t + 1) * IDIM + ln];
            const int u  = ln & 7;
            const int pg = ln >> 3;                    // 8 producer groups of 16
            const float* yb = yx + (size_t)cur * NBLK * YU * 4;
            f32x4 w0,w1,w2,w3,w4,w5,w6,w7,w8,w9,w10,w11,w12,w13,w14,w15;
            for (;;) {
                #define YL(i) asm volatile("global_load_dwordx4 %0, %1, off sc0 sc1" \
                    : "=v"(w##i) : "v"(yb + (((pg << 4) + i) * YU + u) * 4));
                YL(0) YL(1) YL(2) YL(3) YL(4) YL(5) YL(6) YL(7)
                YL(8) YL(9) YL(10) YL(11) YL(12) YL(13) YL(14) YL(15)
                #undef YL
                asm volatile("s_waitcnt vmcnt(0)" ::: "memory");
                __builtin_amdgcn_sched_barrier(0);
                bool ok = __float_as_uint(w0.z) == tu  && __float_as_uint(w1.z) == tu
                       && __float_as_uint(w2.z) == tu  && __float_as_uint(w3.z) == tu
                       && __float_as_uint(w4.z) == tu  && __float_as_uint(w5.z) == tu
                       && __float_as_uint(w6.z) == tu  && __float_as_uint(w7.z) == tu
                       && __float_as_uint(w8.z) == tu  && __float_as_uint(w9.z) == tu
                       && __float_as_uint(w10.z) == tu && __float_as_uint(w11.z) == tu
                       && __float_as_uint(w12.z) == tu && __float_as_uint(w13.z) == tu
                       && __float_as_uint(w14.z) == tu && __float_as_uint(w15.z) == tu;
                if (__all(ok)) break;
            }
            float acc0 = ((w0.x + w1.x) + (w2.x + w3.x)) + ((w4.x + w5.x) + (w6.x + w7.x))
                       + ((w8.x + w9.x) + (w10.x + w11.x)) + ((w12.x + w13.x) + (w14.x + w15.x));
            float acc1 = ((w0.y + w1.y) + (w2.y + w3.y)) + ((w4.y + w5.y) + (w6.y + w7.y))
                       + ((w8.y + w9.y) + (w10.y + w11.y)) + ((w12.y + w13.y) + (w14.y + w15.y));
            acc0 += __shfl_xor(acc0, 8);  acc1 += __shfl_xor(acc1, 8);
            acc0 += __shfl_xor(acc0, 16); acc1 += __shfl_xor(acc1, 16);
            acc0 += __shfl_xor(acc0, 32); acc1 += __shfl_xor(acc1, 32);
            if (ln < 8) {
                if (t + 1 < TSTEPS) { y_lds[nxt][2 * u] = acc0; y_lds[nxt][2 * u + 1] = acc1; }
                if (blk == 0) {
                    out_res[(size_t)t * ODIM + 2 * u]     = acc0;
                    out_res[(size_t)t * ODIM + 2 * u + 1] = acc1;
                }
            }
        } else {
            // ---- s-consumer: 2-deep pipelined poll (vmcnt(3)), halves detect granularity ----
            if (t + 1 < TSTEPS) {
                const int wi    = wv - 2;                        // 0..13
                const int start = (wi < 2) ? wi * 10 : 20 + (wi - 2) * 9;
                const int count = (wi < 2) ? 10 : 9;             // 2*10 + 12*9 = 128
                const int U     = count * SUN;                   // 160 or 144
                const float* sb = sx + ((size_t)cur * NBLK + start) * SUN * 4;
                float* sd = s_lds[nxt];
                const int g0 = ln, g1 = ln + 64, g2r = ln + 128;
                const bool h2 = g2r < U;
                const int g2 = h2 ? g2r : g0;          // clamp: every set = exactly 3 loads
                const float* p0 = sb + (size_t)g0 * 4;
                const float* p1 = sb + (size_t)g1 * 4;
                const float* p2 = sb + (size_t)g2 * 4;
                f32x4 a0, a1, a2, b0, b1, b2;
                #define SISSUE(r0, r1, r2)                                              \
                    asm volatile("global_load_dwordx4 %0, %1, off sc0 sc1" : "=v"(r0) : "v"(p0)); \
                    asm volatile("global_load_dwordx4 %0, %1, off sc0 sc1" : "=v"(r1) : "v"(p1)); \
                    asm volatile("global_load_dwordx4 %0, %1, off sc0 sc1" : "=v"(r2) : "v"(p2));
                #define SCHECK(r0, r1, r2) (__float_as_uint((r0).w) == tu &&            \
                    __float_as_uint((r1).w) == tu && (!h2 || __float_as_uint((r2).w) == tu))
                #define SSCAT(r0, r1, r2) {                                             \
                    { const int pp = start + (g0 >> 4), u_ = g0 & 15;                   \
                      float2 s2; s2.x = (r0).x; s2.y = (r0).y;                          \
                      *(float2*)&sd[pp * SPAD + 2 * u_] = s2; }                         \
                    { const int pp = start + (g1 >> 4), u_ = g1 & 15;                   \
                      float2 s2; s2.x = (r1).x; s2.y = (r1).y;                          \
                      *(float2*)&sd[pp * SPAD + 2 * u_] = s2; }                         \
                    if (h2) { const int pp = start + (g2r >> 4), u_ = g2r & 15;         \
                      float2 s2; s2.x = (r2).x; s2.y = (r2).y;                          \
                      *(float2*)&sd[pp * SPAD + 2 * u_] = s2; } }
                SISSUE(a0, a1, a2)                       // prologue: set A in flight
                for (;;) {
                    SISSUE(b0, b1, b2)                   // keep B in flight
                    asm volatile("s_waitcnt vmcnt(3)" ::: "memory");   // A landed
                    __builtin_amdgcn_sched_barrier(0);
                    if (__all(SCHECK(a0, a1, a2))) { SSCAT(a0, a1, a2); break; }
                    SISSUE(a0, a1, a2)
                    asm volatile("s_waitcnt vmcnt(3)" ::: "memory");   // B landed
                    __builtin_amdgcn_sched_barrier(0);
                    if (__all(SCHECK(b0, b1, b2))) { SSCAT(b0, b1, b2); break; }
                }
                #undef SISSUE
                #undef SCHECK
                #undef SSCAT
                // leftover in-flight loads drain at the barrier below; their regs unused
            }
        }
        __syncthreads();   // A-sync: s/x/y for t+1 ready; gates exchange-buffer reuse
    }
}

extern "C" void kernel_launch(void* const* d_in, const int* in_sizes, int n_in,
                              void* d_out, int out_size, void* d_ws, size_t ws_size,
                              hipStream_t stream) {
    (void)in_sizes; (void)n_in; (void)out_size; (void)ws_size;
    const float* X    = (const float*)d_in[0];
    const float* Win  = (const float*)d_in[1];
    const float* Wres = (const float*)d_in[2];
    const float* b    = (const float*)d_in[3];
    const float* Wfb  = (const float*)d_in[4];
    const float* Wout = (const float*)d_in[5];
    float* out = (float*)d_out;
    float* sx  = (float*)d_ws;                          // 2*128*16*16B = 64 KiB
    float* yx  = (float*)d_ws + 2 * NBLK * SUN * 4;     // 2*128*8*16B  = 32 KiB

    const int words = (2 * NBLK * SUN + 2 * NBLK * YU) * 4;
    init_ws<<<(words + 255) / 256, 256, 0, stream>>>((float*)d_ws);
    esn_kernel<<<NBLK, BLOCK, 0, stream>>>(X, Win, Wres, b, Wfb, Wout, out, sx, yx);
}

// Round 18
// 19708.630 us; speedup vs baseline: 1.3174x; 1.0472x over previous
//
#include <hip/hip_runtime.h>
#include <cstdint>

#define NBLK 128
#define BLOCK 1024
#define ROWS 32            // hidden rows per block: 128*32 = 4096
#define HDIM 4096
#define IDIM 64
#define ODIM 16
#define TSTEPS 4096
#define PAD 576            // 18 groups * 32 slots (bank-dealt ELL)
#define GMAX 18
#define LEAK 0.9f
#define SUN 16             // s units per producer: one per wave {s_2w, s_2w+1, spare, tag}
#define YU 8               // y units per producer: 2 vals + tag + pad
#define SPAD 34            // padded words per 32-value producer chunk in s_lds

typedef float f32x4 __attribute__((ext_vector_type(4)));

// zero the tagged-exchange region every launch (tags use ==, so 0/poison never match)
__global__ void init_ws(float* ws) {
    int i = blockIdx.x * blockDim.x + threadIdx.x;
    if (i < (2 * NBLK * SUN + 2 * NBLK * YU) * 4) ws[i] = 0.0f;
}

__global__ __launch_bounds__(BLOCK) void esn_kernel(
    const float* __restrict__ X,     // [T][I]
    const float* __restrict__ Win,   // [H][I]
    const float* __restrict__ Wres,  // [H][H]
    const float* __restrict__ bvec,  // [H]
    const float* __restrict__ Wfb,   // [H][O]
    const float* __restrict__ Wout,  // [O][H]
    float* __restrict__ out,         // results [T][O] then outputs [T][H]
    float* __restrict__ sx,          // [2][NBLK][SUN] tagged f32x4 units (s exchange)
    float* __restrict__ yx)          // [2][NBLK][YU]  tagged f32x4 units (y partials)
{
    __shared__ float          ell_val[ROWS][PAD];       // 73728 B
    __shared__ unsigned short ell_idx[ROWS][PAD];       // 36864 B (stores PADDED idx)
    __shared__ __align__(16) float s_lds[2][NBLK*SPAD]; // 34816 B (bank-padded chunks)
    __shared__ float          win_lds[ROWS][IDIM];      //  8192 B
    __shared__ float          wfb_lds[ROWS][ODIM];      //  2048 B
    __shared__ __align__(8)  float wout_lds[ROWS][ODIM];//  2048 B ([r][o])
    __shared__ float          b_lds[ROWS];
    __shared__ float          x_lds[2][IDIM];           //  512 B (double buffer)
    __shared__ float          y_lds[2][ODIM];           //  128 B (double buffer)
    __shared__ __align__(8)  float ytmp[16][18];        //  1152 B (per-wave y contribs, padded)
    __shared__ unsigned       done[16];                 // per-wave phase-B completion (LDS)
    __shared__ int            nnz_lds[ROWS];
    __shared__ int            rnds_lds[ROWS];
    __shared__ unsigned char  bankCnt[ROWS][32];        // build only
    __shared__ unsigned char  grpCnt[ROWS][GMAX];       // build only

    const int tid   = threadIdx.x;
    const int blk   = blockIdx.x;
    const int rbase = blk * ROWS;
    const int rowB  = tid >> 5;        // 0..31
    const int lB    = tid & 31;
    const int wv    = tid >> 6;        // 0..15
    const int ln    = tid & 63;

    // ---- pass 0: zero ELL + counters ----
    for (int i = tid; i < ROWS * PAD; i += BLOCK) {
        ell_val[i / PAD][i % PAD] = 0.0f;
        ell_idx[i / PAD][i % PAD] = 0;
    }
    for (int i = tid; i < ROWS * 32; i += BLOCK) bankCnt[i >> 5][i & 31] = 0;
    for (int i = tid; i < ROWS * GMAX; i += BLOCK) grpCnt[i / GMAX][i % GMAX] = 0;
    if (tid < 16) done[tid] = 0u;

    // ---- pass 1 (parallel): nnz per row ----
    for (int rr = wv * 2; rr < wv * 2 + 2; ++rr) {
        const float* wrow = Wres + (size_t)(rbase + rr) * HDIM;
        int cnt = 0;
        for (int c0 = 0; c0 < HDIM; c0 += 64)
            cnt += __popcll(__ballot(wrow[c0 + ln] != 0.0f));
        if (ln == 0) {
            int nz = cnt < PAD ? cnt : PAD;
            nnz_lds[rr] = nz;
            int gu = (nz + 31) >> 5;
            if (gu < 1) gu = 1;
            if (gu > GMAX) gu = GMAX;
            rnds_lds[rr] = (gu + 1) >> 1;
        }
    }
    __syncthreads();

    // ---- pass 2 (serial per row, deterministic): bank-balanced deal on PADDED banks ----
    if (ln == 0 || ln == 32) {
        const int row = wv * 2 + (ln >> 5);
        const int nz  = nnz_lds[row];
        int gu = (nz + 31) >> 5;
        if (gu < 1) gu = 1;
        if (gu > GMAX) gu = GMAX;
        const float* wrow = Wres + (size_t)(rbase + row) * HDIM;
        int placed = 0;
        for (int c = 0; c < HDIM && placed < nz; ++c) {
            const float w = wrow[c];
            if (w != 0.0f) {
                const int pidx = c + 2 * (c >> 5);       // padded word index (SPAD=34)
                const int b = pidx & 31;                 // bank of the padded gather
                const int r = bankCnt[row][b];
                bankCnt[row][b] = (unsigned char)(r + 1);
                int g = r % gu;
                int p = grpCnt[row][g];
                int guard = 0;
                while (p >= 32 && guard < GMAX) {
                    g = (g + 1 == gu) ? 0 : g + 1;
                    p = grpCnt[row][g];
                    ++guard;
                }
                if (p >= 32) break;
                grpCnt[row][g] = (unsigned char)(p + 1);
                const int slot = ((g >> 1) << 6) + 2 * p + (g & 1);
                ell_val[row][slot] = w;
                ell_idx[row][slot] = (unsigned short)pidx;
                ++placed;
            }
        }
    }

    // ---- small weights into LDS ----
    for (int i = tid; i < ROWS * IDIM; i += BLOCK)
        win_lds[i >> 6][i & 63] = Win[(size_t)(rbase + (i >> 6)) * IDIM + (i & 63)];
    for (int i = tid; i < ROWS * ODIM; i += BLOCK)
        wfb_lds[i >> 4][i & 15] = Wfb[(size_t)(rbase + (i >> 4)) * ODIM + (i & 15)];
    for (int i = tid; i < ROWS * ODIM; i += BLOCK)   // [r][o] = Wout[o][rbase+r]
        wout_lds[i >> 4][i & 15] = Wout[(size_t)(i & 15) * HDIM + rbase + (i >> 4)];
    if (tid < ROWS) b_lds[tid] = bvec[rbase + tid];

    // ---- prologue: s_{-1}=0 (both buffers, flat), y_{-1}=0, x_0 ----
    {
        float* sz = &s_lds[0][0];
        for (int i = tid; i < 2 * NBLK * SPAD; i += BLOCK) sz[i] = 0.0f;
    }
    if (tid < ODIM) y_lds[0][tid] = 0.0f;
    if (tid >= 64 && tid < 128) x_lds[0][tid - 64] = X[tid - 64];
    __syncthreads();

    float* out_res = out;
    float* out_s   = out + (size_t)TSTEPS * ODIM;
    const int RB = rnds_lds[rowB];

    for (int t = 0; t < TSTEPS; ++t) {
        const unsigned tu = (unsigned)(t + 1);
        const float tagf = __uint_as_float(tu);
        const int cur = t & 1, nxt = cur ^ 1;

        // ---- phase B: gather, reduce; per-wave INLINE publish of s-unit + y-contrib ----
        {
            const float* sc = s_lds[cur];
            float a0 = 0.0f, a1 = 0.0f;
            for (int k = 0; k < RB; ++k) {
                const int e = (k << 6) + (lB << 1);
                const float2  v  = *(const float2*)&ell_val[rowB][e];
                const ushort2 ix = *(const ushort2*)&ell_idx[rowB][e];  // padded idx
                a0 += v.x * sc[ix.x];
                a1 += v.y * sc[ix.y];
            }
            float acc = a0 + a1;
            acc += win_lds[rowB][lB] * x_lds[cur][lB]
                 + win_lds[rowB][lB + 32] * x_lds[cur][lB + 32];
            if (lB < ODIM) acc += wfb_lds[rowB][lB] * y_lds[cur][lB];
            acc += __shfl_xor(acc, 16, 32);
            acc += __shfl_xor(acc, 8, 32);
            acc += __shfl_xor(acc, 4, 32);
            acc += __shfl_xor(acc, 2, 32);
            acc += __shfl_xor(acc, 1, 32);
            // all lanes of each 32-half now hold the row sum
            const float pre = acc + b_lds[rowB];
            const float snAll = (1.0f - LEAK) * sc[blk * SPAD + rowB] + LEAK * tanhf(pre);
            const float sn0 = __shfl(snAll, 0);    // row 2w
            const float sn1 = __shfl(snAll, 32);   // row 2w+1
            if (ln < 16)                           // wave's y contribution (order = r asc)
                ytmp[wv][ln] = wout_lds[2 * wv][ln] * sn0 + wout_lds[2 * wv + 1][ln] * sn1;
            if (ln == 0) {
                f32x4 v; v.x = sn0; v.y = sn1; v.z = 0.0f; v.w = tagf;   // tag in .w
                float* dst = sx + (((size_t)cur * NBLK + blk) * SUN + wv) * 4;
                asm volatile("global_store_dwordx4 %0, %1, off sc0 sc1 nt"
                             :: "v"(dst), "v"(v) : "memory");
                float2 o2; o2.x = sn0; o2.y = sn1;   // out_s (plain cached store)
                *(float2*)(out_s + (size_t)t * HDIM + rbase + 2 * wv) = o2;
                __hip_atomic_store(&done[wv], tu, __ATOMIC_RELEASE,
                                   __HIP_MEMORY_SCOPE_WORKGROUP);  // orders ytmp writes
            }
        }
        // NO B-sync: waves proceed straight to their exchange roles.

        if (wv == 0) {
            // ---- y publisher: wait 16 LDS flags (cheap), sum ytmp, publish units ----
            for (;;) {
                unsigned f = (ln < 16)
                    ? __hip_atomic_load(&done[ln], __ATOMIC_ACQUIRE, __HIP_MEMORY_SCOPE_WORKGROUP)
                    : tu;
                if (__all(f >= tu)) break;
            }
            if (ln < YU) {
                float a0 = 0.0f, a1 = 0.0f;
                #pragma unroll
                for (int w = 0; w < 16; ++w) {       // order = w asc = r asc
                    const float2 p = *(const float2*)&ytmp[w][2 * ln];
                    a0 += p.x;
                    a1 += p.y;
                }
                f32x4 v; v.x = a0; v.y = a1; v.z = tagf; v.w = 0.0f;   // tag in .z
                float* dst = yx + (((size_t)cur * NBLK + blk) * YU + ln) * 4;
                asm volatile("global_store_dwordx4 %0, %1, off sc0 sc1 nt"
                             :: "v"(dst), "v"(v) : "memory");
            }
        } else if (wv == 1) {
            // ---- y-reduce: x[nxt] prefetch; poll all 128 y units; butterfly ----
            if (t + 1 < TSTEPS) x_lds[nxt][ln] = X[(size_t)(t + 1) * IDIM + ln];
            const int u  = ln & 7;
            const int pg = ln >> 3;                    // 8 producer groups of 16
            const float* yb = yx + (size_t)cur * NBLK * YU * 4;
            f32x4 w0,w1,w2,w3,w4,w5,w6,w7,w8,w9,w10,w11,w12,w13,w14,w15;
            for (;;) {
                #define YL(i) asm volatile("global_load_dwordx4 %0, %1, off sc0 sc1" \
                    : "=v"(w##i) : "v"(yb + (((pg << 4) + i) * YU + u) * 4));
                YL(0) YL(1) YL(2) YL(3) YL(4) YL(5) YL(6) YL(7)
                YL(8) YL(9) YL(10) YL(11) YL(12) YL(13) YL(14) YL(15)
                #undef YL
                asm volatile("s_waitcnt vmcnt(0)" ::: "memory");
                __builtin_amdgcn_sched_barrier(0);
                bool ok = __float_as_uint(w0.z) == tu  && __float_as_uint(w1.z) == tu
                       && __float_as_uint(w2.z) == tu  && __float_as_uint(w3.z) == tu
                       && __float_as_uint(w4.z) == tu  && __float_as_uint(w5.z) == tu
                       && __float_as_uint(w6.z) == tu  && __float_as_uint(w7.z) == tu
                       && __float_as_uint(w8.z) == tu  && __float_as_uint(w9.z) == tu
                       && __float_as_uint(w10.z) == tu && __float_as_uint(w11.z) == tu
                       && __float_as_uint(w12.z) == tu && __float_as_uint(w13.z) == tu
                       && __float_as_uint(w14.z) == tu && __float_as_uint(w15.z) == tu;
                if (__all(ok)) break;
            }
            float acc0 = ((w0.x + w1.x) + (w2.x + w3.x)) + ((w4.x + w5.x) + (w6.x + w7.x))
                       + ((w8.x + w9.x) + (w10.x + w11.x)) + ((w12.x + w13.x) + (w14.x + w15.x));
            float acc1 = ((w0.y + w1.y) + (w2.y + w3.y)) + ((w4.y + w5.y) + (w6.y + w7.y))
                       + ((w8.y + w9.y) + (w10.y + w11.y)) + ((w12.y + w13.y) + (w14.y + w15.y));
            acc0 += __shfl_xor(acc0, 8);  acc1 += __shfl_xor(acc1, 8);
            acc0 += __shfl_xor(acc0, 16); acc1 += __shfl_xor(acc1, 16);
            acc0 += __shfl_xor(acc0, 32); acc1 += __shfl_xor(acc1, 32);
            if (ln < 8) {
                if (t + 1 < TSTEPS) { y_lds[nxt][2 * u] = acc0; y_lds[nxt][2 * u + 1] = acc1; }
                if (blk == 0) {
                    out_res[(size_t)t * ODIM + 2 * u]     = acc0;
                    out_res[(size_t)t * ODIM + 2 * u + 1] = acc1;
                }
            }
        } else {
            // ---- s-consumer: poll this wave's slice of per-wave units; padded scatter ----
            if (t + 1 < TSTEPS) {
                const int wi    = wv - 2;                        // 0..13
                const int start = (wi < 2) ? wi * 10 : 20 + (wi - 2) * 9;
                const int count = (wi < 2) ? 10 : 9;             // 2*10 + 12*9 = 128
                const int U     = count * SUN;                   // 160 or 144
                const float* sb = sx + ((size_t)cur * NBLK + start) * SUN * 4;
                const int g0 = ln, g1 = ln + 64, g2 = ln + 128;
                const bool h1 = g1 < U, h2 = g2 < U;
                f32x4 v0, v1, v2;
                for (;;) {
                    asm volatile("global_load_dwordx4 %0, %1, off sc0 sc1"
                                 : "=v"(v0) : "v"(sb + (size_t)g0 * 4));
                    if (h1)
                        asm volatile("global_load_dwordx4 %0, %1, off sc0 sc1"
                                     : "=v"(v1) : "v"(sb + (size_t)g1 * 4));
                    if (h2)
                        asm volatile("global_load_dwordx4 %0, %1, off sc0 sc1"
                                     : "=v"(v2) : "v"(sb + (size_t)g2 * 4));
                    asm volatile("s_waitcnt vmcnt(0)" ::: "memory");
                    __builtin_amdgcn_sched_barrier(0);
                    bool ok = (__float_as_uint(v0.w) == tu)
                           && (!h1 || __float_as_uint(v1.w) == tu)
                           && (!h2 || __float_as_uint(v2.w) == tu);
                    if (__all(ok)) break;
                }
                float* sd = s_lds[nxt];
                {   const int pp = start + (g0 >> 4), u = g0 & 15;
                    float2 s2; s2.x = v0.x; s2.y = v0.y;
                    *(float2*)&sd[pp * SPAD + 2 * u] = s2; }
                if (h1) {
                    const int pp = start + (g1 >> 4), u = g1 & 15;
                    float2 s2; s2.x = v1.x; s2.y = v1.y;
                    *(float2*)&sd[pp * SPAD + 2 * u] = s2; }
                if (h2) {
                    const int pp = start + (g2 >> 4), u = g2 & 15;
                    float2 s2; s2.x = v2.x; s2.y = v2.y;
                    *(float2*)&sd[pp * SPAD + 2 * u] = s2; }
            }
        }
        __syncthreads();   // A-sync: s/x/y for t+1 ready; gates exchange-buffer reuse
    }
}

extern "C" void kernel_launch(void* const* d_in, const int* in_sizes, int n_in,
                              void* d_out, int out_size, void* d_ws, size_t ws_size,
                              hipStream_t stream) {
    (void)in_sizes; (void)n_in; (void)out_size; (void)ws_size;
    const float* X    = (const float*)d_in[0];
    const float* Win  = (const float*)d_in[1];
    const float* Wres = (const float*)d_in[2];
    const float* b    = (const float*)d_in[3];
    const float* Wfb  = (const float*)d_in[4];
    const float* Wout = (const float*)d_in[5];
    float* out = (float*)d_out;
    float* sx  = (float*)d_ws;                          // 2*128*16*16B = 64 KiB
    float* yx  = (float*)d_ws + 2 * NBLK * SUN * 4;     // 2*128*8*16B  = 32 KiB

    const int words = (2 * NBLK * SUN + 2 * NBLK * YU) * 4;
    init_ws<<<(words + 255) / 256, 256, 0, stream>>>((float*)d_ws);
    esn_kernel<<<NBLK, BLOCK, 0, stream>>>(X, Win, Wres, b, Wfb, Wout, out, sx, yx);
}

// Round 19
// 18842.468 us; speedup vs baseline: 1.3779x; 1.0460x over previous
//
#include <hip/hip_runtime.h>
#include <cstdint>

#define NBLK 128
#define BLOCK 1024
#define ROWS 32            // hidden rows per block: 128*32 = 4096
#define HDIM 4096
#define IDIM 64
#define ODIM 16
#define TSTEPS 4096
#define PAD 576            // 18 groups * 32 slots (bank-dealt ELL)
#define GMAX 18
#define LEAK 0.9f
#define SUN 16             // s units per producer: one per wave {s_2w, s_2w+1, spare, tag}
#define YU 8               // y units per producer: 2 vals + tag + pad
#define SPAD 34            // padded words per 32-value producer chunk in s_lds

typedef float f32x4 __attribute__((ext_vector_type(4)));

// zero the tagged-exchange region every launch (tags use ==, so 0/poison never match)
__global__ void init_ws(float* ws) {
    int i = blockIdx.x * blockDim.x + threadIdx.x;
    if (i < (2 * NBLK * SUN + 2 * NBLK * YU) * 4) ws[i] = 0.0f;
}

__global__ __launch_bounds__(BLOCK) void esn_kernel(
    const float* __restrict__ X,     // [T][I]
    const float* __restrict__ Win,   // [H][I]
    const float* __restrict__ Wres,  // [H][H]
    const float* __restrict__ bvec,  // [H]
    const float* __restrict__ Wfb,   // [H][O]
    const float* __restrict__ Wout,  // [O][H]
    float* __restrict__ out,         // results [T][O] then outputs [T][H]
    float* __restrict__ sx,          // [2][NBLK][SUN] tagged f32x4 units (s exchange)
    float* __restrict__ yx)          // [2][NBLK][YU]  tagged f32x4 units (y partials)
{
    __shared__ float          ell_val[ROWS][PAD];       // 73728 B
    __shared__ unsigned short ell_idx[ROWS][PAD];       // 36864 B (stores PADDED idx)
    __shared__ __align__(16) float s_lds[2][NBLK*SPAD]; // 34816 B (bank-padded chunks)
    __shared__ float          win_lds[ROWS][IDIM];      //  8192 B
    __shared__ float          wfb_lds[ROWS][ODIM];      //  2048 B
    __shared__ __align__(8)  float wout_lds[ROWS][ODIM];//  2048 B ([r][o])
    __shared__ float          b_lds[ROWS];
    __shared__ float          x_lds[2][IDIM];           //  512 B (double buffer)
    __shared__ float          y_lds[2][ODIM];           //  128 B (double buffer)
    __shared__ __align__(8)  float ytmp[16][18];        //  1152 B (per-wave y contribs, padded)
    __shared__ unsigned       done[16];                 // per-wave phase-B completion (LDS)
    __shared__ int            nnz_lds[ROWS];
    __shared__ int            rnds_lds[ROWS];
    __shared__ unsigned char  bankCnt[ROWS][32];        // build only
    __shared__ unsigned char  grpCnt[ROWS][GMAX];       // build only

    const int tid   = threadIdx.x;
    const int blk   = blockIdx.x;
    const int rbase = blk * ROWS;
    const int rowB  = tid >> 5;        // 0..31
    const int lB    = tid & 31;
    const int wv    = tid >> 6;        // 0..15
    const int ln    = tid & 63;

    // ---- pass 0: zero ELL + counters ----
    for (int i = tid; i < ROWS * PAD; i += BLOCK) {
        ell_val[i / PAD][i % PAD] = 0.0f;
        ell_idx[i / PAD][i % PAD] = 0;
    }
    for (int i = tid; i < ROWS * 32; i += BLOCK) bankCnt[i >> 5][i & 31] = 0;
    for (int i = tid; i < ROWS * GMAX; i += BLOCK) grpCnt[i / GMAX][i % GMAX] = 0;
    if (tid < 16) done[tid] = 0u;

    // ---- pass 1 (parallel): nnz per row ----
    for (int rr = wv * 2; rr < wv * 2 + 2; ++rr) {
        const float* wrow = Wres + (size_t)(rbase + rr) * HDIM;
        int cnt = 0;
        for (int c0 = 0; c0 < HDIM; c0 += 64)
            cnt += __popcll(__ballot(wrow[c0 + ln] != 0.0f));
        if (ln == 0) {
            int nz = cnt < PAD ? cnt : PAD;
            nnz_lds[rr] = nz;
            int gu = (nz + 31) >> 5;
            if (gu < 1) gu = 1;
            if (gu > GMAX) gu = GMAX;
            rnds_lds[rr] = (gu + 1) >> 1;
        }
    }
    __syncthreads();

    // ---- pass 2 (serial per row, deterministic): bank-balanced deal on PADDED banks ----
    if (ln == 0 || ln == 32) {
        const int row = wv * 2 + (ln >> 5);
        const int nz  = nnz_lds[row];
        int gu = (nz + 31) >> 5;
        if (gu < 1) gu = 1;
        if (gu > GMAX) gu = GMAX;
        const float* wrow = Wres + (size_t)(rbase + row) * HDIM;
        int placed = 0;
        for (int c = 0; c < HDIM && placed < nz; ++c) {
            const float w = wrow[c];
            if (w != 0.0f) {
                const int pidx = c + 2 * (c >> 5);       // padded word index (SPAD=34)
                const int b = pidx & 31;                 // bank of the padded gather
                const int r = bankCnt[row][b];
                bankCnt[row][b] = (unsigned char)(r + 1);
                int g = r % gu;
                int p = grpCnt[row][g];
                int guard = 0;
                while (p >= 32 && guard < GMAX) {
                    g = (g + 1 == gu) ? 0 : g + 1;
                    p = grpCnt[row][g];
                    ++guard;
                }
                if (p >= 32) break;
                grpCnt[row][g] = (unsigned char)(p + 1);
                const int slot = ((g >> 1) << 6) + 2 * p + (g & 1);
                ell_val[row][slot] = w;
                ell_idx[row][slot] = (unsigned short)pidx;
                ++placed;
            }
        }
    }

    // ---- small weights into LDS ----
    for (int i = tid; i < ROWS * IDIM; i += BLOCK)
        win_lds[i >> 6][i & 63] = Win[(size_t)(rbase + (i >> 6)) * IDIM + (i & 63)];
    for (int i = tid; i < ROWS * ODIM; i += BLOCK)
        wfb_lds[i >> 4][i & 15] = Wfb[(size_t)(rbase + (i >> 4)) * ODIM + (i & 15)];
    for (int i = tid; i < ROWS * ODIM; i += BLOCK)   // [r][o] = Wout[o][rbase+r]
        wout_lds[i >> 4][i & 15] = Wout[(size_t)(i & 15) * HDIM + rbase + (i >> 4)];
    if (tid < ROWS) b_lds[tid] = bvec[rbase + tid];

    // ---- prologue: s_{-1}=0 (both buffers, flat), y_{-1}=0, x_0 ----
    {
        float* sz = &s_lds[0][0];
        for (int i = tid; i < 2 * NBLK * SPAD; i += BLOCK) sz[i] = 0.0f;
    }
    if (tid < ODIM) y_lds[0][tid] = 0.0f;
    if (tid >= 64 && tid < 128) x_lds[0][tid - 64] = X[tid - 64];
    __syncthreads();

    float* out_res = out;
    float* out_s   = out + (size_t)TSTEPS * ODIM;
    const int RB = rnds_lds[rowB];

    for (int t = 0; t < TSTEPS; ++t) {
        const unsigned tu = (unsigned)(t + 1);
        const float tagf = __uint_as_float(tu);
        const int cur = t & 1, nxt = cur ^ 1;

        // ---- phase B: gather, reduce; per-wave INLINE publish of s-unit + y-contrib ----
        {
            const float* sc = s_lds[cur];
            float a0 = 0.0f, a1 = 0.0f;
            for (int k = 0; k < RB; ++k) {
                const int e = (k << 6) + (lB << 1);
                const float2  v  = *(const float2*)&ell_val[rowB][e];
                const ushort2 ix = *(const ushort2*)&ell_idx[rowB][e];  // padded idx
                a0 += v.x * sc[ix.x];
                a1 += v.y * sc[ix.y];
            }
            float acc = a0 + a1;
            acc += win_lds[rowB][lB] * x_lds[cur][lB]
                 + win_lds[rowB][lB + 32] * x_lds[cur][lB + 32];
            if (lB < ODIM) acc += wfb_lds[rowB][lB] * y_lds[cur][lB];
            acc += __shfl_xor(acc, 16, 32);
            acc += __shfl_xor(acc, 8, 32);
            acc += __shfl_xor(acc, 4, 32);
            acc += __shfl_xor(acc, 2, 32);
            acc += __shfl_xor(acc, 1, 32);
            // all lanes of each 32-half now hold the row sum
            const float pre = acc + b_lds[rowB];
            const float snAll = (1.0f - LEAK) * sc[blk * SPAD + rowB] + LEAK * tanhf(pre);
            const float sn0 = __shfl(snAll, 0);    // row 2w
            const float sn1 = __shfl(snAll, 32);   // row 2w+1
            if (ln < 16)                           // wave's y contribution (order = r asc)
                ytmp[wv][ln] = wout_lds[2 * wv][ln] * sn0 + wout_lds[2 * wv + 1][ln] * sn1;
            if (ln == 0) {
                f32x4 v; v.x = sn0; v.y = sn1; v.z = 0.0f; v.w = tagf;   // tag in .w
                float* dst = sx + (((size_t)cur * NBLK + blk) * SUN + wv) * 4;
                asm volatile("global_store_dwordx4 %0, %1, off sc0 sc1"
                             :: "v"(dst), "v"(v) : "memory");
                float2 o2; o2.x = sn0; o2.y = sn1;   // out_s (plain cached store)
                *(float2*)(out_s + (size_t)t * HDIM + rbase + 2 * wv) = o2;
                __hip_atomic_store(&done[wv], tu, __ATOMIC_RELEASE,
                                   __HIP_MEMORY_SCOPE_WORKGROUP);  // orders ytmp writes
            }
        }
        // NO B-sync: waves proceed straight to their exchange roles.

        if (wv == 0) {
            // ---- y publisher: wait 16 LDS flags (cheap), sum ytmp, publish units ----
            for (;;) {
                unsigned f = (ln < 16)
                    ? __hip_atomic_load(&done[ln], __ATOMIC_ACQUIRE, __HIP_MEMORY_SCOPE_WORKGROUP)
                    : tu;
                if (__all(f >= tu)) break;
            }
            if (ln < YU) {
                float a0 = 0.0f, a1 = 0.0f;
                #pragma unroll
                for (int w = 0; w < 16; ++w) {       // order = w asc = r asc
                    const float2 p = *(const float2*)&ytmp[w][2 * ln];
                    a0 += p.x;
                    a1 += p.y;
                }
                f32x4 v; v.x = a0; v.y = a1; v.z = tagf; v.w = 0.0f;   // tag in .z
                float* dst = yx + (((size_t)cur * NBLK + blk) * YU + ln) * 4;
                asm volatile("global_store_dwordx4 %0, %1, off sc0 sc1"
                             :: "v"(dst), "v"(v) : "memory");
            }
        } else if (wv == 1) {
            // ---- y-reduce: x[nxt] prefetch; poll all 128 y units; butterfly ----
            if (t + 1 < TSTEPS) x_lds[nxt][ln] = X[(size_t)(t + 1) * IDIM + ln];
            const int u  = ln & 7;
            const int pg = ln >> 3;                    // 8 producer groups of 16
            const float* yb = yx + (size_t)cur * NBLK * YU * 4;
            f32x4 w0,w1,w2,w3,w4,w5,w6,w7,w8,w9,w10,w11,w12,w13,w14,w15;
            for (;;) {
                #define YL(i) asm volatile("global_load_dwordx4 %0, %1, off sc0 sc1" \
                    : "=v"(w##i) : "v"(yb + (((pg << 4) + i) * YU + u) * 4));
                YL(0) YL(1) YL(2) YL(3) YL(4) YL(5) YL(6) YL(7)
                YL(8) YL(9) YL(10) YL(11) YL(12) YL(13) YL(14) YL(15)
                #undef YL
                asm volatile("s_waitcnt vmcnt(0)" ::: "memory");
                __builtin_amdgcn_sched_barrier(0);
                bool ok = __float_as_uint(w0.z) == tu  && __float_as_uint(w1.z) == tu
                       && __float_as_uint(w2.z) == tu  && __float_as_uint(w3.z) == tu
                       && __float_as_uint(w4.z) == tu  && __float_as_uint(w5.z) == tu
                       && __float_as_uint(w6.z) == tu  && __float_as_uint(w7.z) == tu
                       && __float_as_uint(w8.z) == tu  && __float_as_uint(w9.z) == tu
                       && __float_as_uint(w10.z) == tu && __float_as_uint(w11.z) == tu
                       && __float_as_uint(w12.z) == tu && __float_as_uint(w13.z) == tu
                       && __float_as_uint(w14.z) == tu && __float_as_uint(w15.z) == tu;
                if (__all(ok)) break;
            }
            float acc0 = ((w0.x + w1.x) + (w2.x + w3.x)) + ((w4.x + w5.x) + (w6.x + w7.x))
                       + ((w8.x + w9.x) + (w10.x + w11.x)) + ((w12.x + w13.x) + (w14.x + w15.x));
            float acc1 = ((w0.y + w1.y) + (w2.y + w3.y)) + ((w4.y + w5.y) + (w6.y + w7.y))
                       + ((w8.y + w9.y) + (w10.y + w11.y)) + ((w12.y + w13.y) + (w14.y + w15.y));
            acc0 += __shfl_xor(acc0, 8);  acc1 += __shfl_xor(acc1, 8);
            acc0 += __shfl_xor(acc0, 16); acc1 += __shfl_xor(acc1, 16);
            acc0 += __shfl_xor(acc0, 32); acc1 += __shfl_xor(acc1, 32);
            if (ln < 8) {
                if (t + 1 < TSTEPS) { y_lds[nxt][2 * u] = acc0; y_lds[nxt][2 * u + 1] = acc1; }
                if (blk == 0) {
                    out_res[(size_t)t * ODIM + 2 * u]     = acc0;
                    out_res[(size_t)t * ODIM + 2 * u + 1] = acc1;
                }
            }
        } else {
            // ---- s-consumer: poll this wave's slice of per-wave units; padded scatter ----
            if (t + 1 < TSTEPS) {
                const int wi    = wv - 2;                        // 0..13
                const int start = (wi < 2) ? wi * 10 : 20 + (wi - 2) * 9;
                const int count = (wi < 2) ? 10 : 9;             // 2*10 + 12*9 = 128
                const int U     = count * SUN;                   // 160 or 144
                const float* sb = sx + ((size_t)cur * NBLK + start) * SUN * 4;
                const int g0 = ln, g1 = ln + 64, g2 = ln + 128;
                const bool h1 = g1 < U, h2 = g2 < U;
                f32x4 v0, v1, v2;
                for (;;) {
                    asm volatile("global_load_dwordx4 %0, %1, off sc0 sc1"
                                 : "=v"(v0) : "v"(sb + (size_t)g0 * 4));
                    if (h1)
                        asm volatile("global_load_dwordx4 %0, %1, off sc0 sc1"
                                     : "=v"(v1) : "v"(sb + (size_t)g1 * 4));
                    if (h2)
                        asm volatile("global_load_dwordx4 %0, %1, off sc0 sc1"
                                     : "=v"(v2) : "v"(sb + (size_t)g2 * 4));
                    asm volatile("s_waitcnt vmcnt(0)" ::: "memory");
                    __builtin_amdgcn_sched_barrier(0);
                    bool ok = (__float_as_uint(v0.w) == tu)
                           && (!h1 || __float_as_uint(v1.w) == tu)
                           && (!h2 || __float_as_uint(v2.w) == tu);
                    if (__all(ok)) break;
                }
                float* sd = s_lds[nxt];
                {   const int pp = start + (g0 >> 4), u = g0 & 15;
                    float2 s2; s2.x = v0.x; s2.y = v0.y;
                    *(float2*)&sd[pp * SPAD + 2 * u] = s2; }
                if (h1) {
                    const int pp = start + (g1 >> 4), u = g1 & 15;
                    float2 s2; s2.x = v1.x; s2.y = v1.y;
                    *(float2*)&sd[pp * SPAD + 2 * u] = s2; }
                if (h2) {
                    const int pp = start + (g2 >> 4), u = g2 & 15;
                    float2 s2; s2.x = v2.x; s2.y = v2.y;
                    *(float2*)&sd[pp * SPAD + 2 * u] = s2; }
            }
        }
        __syncthreads();   // A-sync: s/x/y for t+1 ready; gates exchange-buffer reuse
    }
}

extern "C" void kernel_launch(void* const* d_in, const int* in_sizes, int n_in,
                              void* d_out, int out_size, void* d_ws, size_t ws_size,
                              hipStream_t stream) {
    (void)in_sizes; (void)n_in; (void)out_size; (void)ws_size;
    const float* X    = (const float*)d_in[0];
    const float* Win  = (const float*)d_in[1];
    const float* Wres = (const float*)d_in[2];
    const float* b    = (const float*)d_in[3];
    const float* Wfb  = (const float*)d_in[4];
    const float* Wout = (const float*)d_in[5];
    float* out = (float*)d_out;
    float* sx  = (float*)d_ws;                          // 2*128*16*16B = 64 KiB
    float* yx  = (float*)d_ws + 2 * NBLK * SUN * 4;     // 2*128*8*16B  = 32 KiB

    const int words = (2 * NBLK * SUN + 2 * NBLK * YU) * 4;
    init_ws<<<(words + 255) / 256, 256, 0, stream>>>((float*)d_ws);
    esn_kernel<<<NBLK, BLOCK, 0, stream>>>(X, Win, Wres, b, Wfb, Wout, out, sx, yx);
}